// Round 8
// baseline (498.160 us; speedup 1.0000x reference)
//
#include <hip/hip_runtime.h>
#include <math.h>

#define N_NODES 100000
#define N_EDGES 1600000
#define NEG_SLOPE 0.2f

// ============================================================================
// k1: per-node projection feat = x @ W, attention logits el/er; zero the
//     degree counters and the global segment cursor.  One wave per node.
// ============================================================================
__global__ __launch_bounds__(256) void k1_project(
        const float* __restrict__ x, const float* __restrict__ W,
        const float* __restrict__ attn_l, const float* __restrict__ attn_r,
        float* __restrict__ feat, float* __restrict__ el, float* __restrict__ er,
        int* __restrict__ cursor, int* __restrict__ gtotal) {
    __shared__ float Ws[64 * 64];
    int t = threadIdx.x;
    for (int i = t; i < 1024; i += 256)                 // stage W (16 KB) via float4
        ((float4*)Ws)[i] = ((const float4*)W)[i];
    if (blockIdx.x == 0 && t == 0) *gtotal = 0;
    __syncthreads();

    int lane = t & 63;
    int wib  = t >> 6;                                  // wave in block, 0..3
    int h    = lane >> 4;
    float al = attn_l[lane];                            // attn_l is flat [4*16]
    float ar = attn_r[lane];
    int wavesTotal = (gridDim.x * blockDim.x) >> 6;

    for (int n = blockIdx.x * 4 + wib; n < N_NODES; n += wavesTotal) {
        float xv  = x[n * 64 + lane];
        float acc = 0.f;
        #pragma unroll
        for (int k = 0; k < 64; ++k) {
            float xk = __shfl(xv, k, 64);               // broadcast x[n][k]
            acc = fmaf(xk, Ws[k * 64 + lane], acc);
        }
        feat[n * 64 + lane] = acc;
        float vl = acc * al, vr = acc * ar;
        #pragma unroll
        for (int off = 8; off >= 1; off >>= 1) {        // reduce within 16-lane head group
            vl += __shfl_xor(vl, off, 64);
            vr += __shfl_xor(vr, off, 64);
        }
        if ((lane & 15) == 0) {
            el[n * 4 + h] = vl;
            er[n * 4 + h] = vr;
        }
        if (lane == 0) cursor[n] = 0;                   // zero degree counter
    }
}

// ============================================================================
// k2: degree histogram — cursor[d] = in-degree(d).
//     4 edges/thread via int4: 4 independent atomic chains per thread (MLP).
// ============================================================================
__global__ __launch_bounds__(256) void k2_hist(
        const int* __restrict__ dst, int* __restrict__ cursor) {
    int t = blockIdx.x * blockDim.x + threadIdx.x;
    if (t >= N_EDGES / 4) return;
    int4 d = ((const int4*)dst)[t];                     // 16B coalesced
    atomicAdd(&cursor[d.x], 1);
    atomicAdd(&cursor[d.y], 1);
    atomicAdd(&cursor[d.z], 1);
    atomicAdd(&cursor[d.w], 1);
}

// ============================================================================
// k3: assign each node a contiguous segment [start, start+deg).
//     Segment ORDER across nodes is irrelevant, so no full prefix scan:
//     wave-local prefix via shfl + ONE global atomicAdd per wave.
//     rowptr[n] = start; cursor[n] = start (becomes fill cursor).
// ============================================================================
__global__ __launch_bounds__(256) void k3_segbase(
        int* __restrict__ cursor, int* __restrict__ rowptr, int* __restrict__ gtotal) {
    int tid  = blockIdx.x * blockDim.x + threadIdx.x;
    int lane = threadIdx.x & 63;
    int n    = tid;
    int deg  = (n < N_NODES) ? cursor[n] : 0;
    // inclusive wave prefix sum
    int incl = deg;
    #pragma unroll
    for (int off = 1; off < 64; off <<= 1) {
        int v = __shfl_up(incl, off, 64);
        if (lane >= off) incl += v;
    }
    int waveTotal = __shfl(incl, 63, 64);
    int base = 0;
    if (lane == 63) base = atomicAdd(gtotal, waveTotal);
    base = __shfl(base, 63, 64);
    int start = base + incl - deg;                      // exclusive prefix
    if (n < N_NODES) {
        rowptr[n] = start;
        cursor[n] = start;
    }
}

// ============================================================================
// k4: fill — edge_src[pos] = src, pos = cursor[dst]++.
//     4 edges/thread via int4: the atomic->dependent-scattered-write chain is
//     latency-bound (VALUBusy 0.3%, 11% HBM); 4 independent chains/thread
//     overlap the L2 atomic + write latencies.
// ============================================================================
__global__ __launch_bounds__(256) void k4_fill(
        const int* __restrict__ src, const int* __restrict__ dst,
        int* __restrict__ cursor, int* __restrict__ edge_src) {
    int t = blockIdx.x * blockDim.x + threadIdx.x;
    if (t >= N_EDGES / 4) return;
    int4 s = ((const int4*)src)[t];                     // 16B coalesced
    int4 d = ((const int4*)dst)[t];
    int p0 = atomicAdd(&cursor[d.x], 1);                // 4 independent chains
    int p1 = atomicAdd(&cursor[d.y], 1);
    int p2 = atomicAdd(&cursor[d.z], 1);
    int p3 = atomicAdd(&cursor[d.w], 1);
    edge_src[p0] = s.x;
    edge_src[p1] = s.y;
    edge_src[p2] = s.z;
    edge_src[p3] = s.w;
}

// ============================================================================
// k5: gather-aggregate with online softmax.  One wave per dst node.
//     Lane f owns feature f (head h = f>>4).  After k4, cursor[n] == segment
//     end.  No atomics anywhere; epilogue (divide + bias) fused.
// ============================================================================
__global__ __launch_bounds__(256) void k5_gather(
        const int* __restrict__ rowptr, const int* __restrict__ cursor,
        const int* __restrict__ edge_src,
        const float* __restrict__ el, const float* __restrict__ er,
        const float* __restrict__ feat, const float* __restrict__ bias,
        float* __restrict__ out) {
    int lane = threadIdx.x & 63;
    int h    = lane >> 4;
    int n    = (blockIdx.x * blockDim.x + threadIdx.x) >> 6;   // wave id == node
    if (n >= N_NODES) return;

    int   row0 = rowptr[n];                              // broadcast loads
    int   row1 = cursor[n];
    float er_h = er[n * 4 + h];
    float bv   = bias[lane];

    float m = -INFINITY, denom = 0.f, acc = 0.f;
    for (int base = row0; base < row1; base += 64) {
        int nchunk = min(64, row1 - base);
        int sv = (base + lane < row1) ? edge_src[base + lane] : 0;  // coalesced
        for (int j = 0; j < nchunk; ++j) {
            int   s  = __shfl(sv, j, 64);
            float v  = el[s * 4 + h] + er_h;             // 16-lane broadcast load
            v = v > 0.f ? v : NEG_SLOPE * v;             // leaky relu
            float fa = feat[s * 64 + lane];              // coalesced 256B gather
            // online softmax update
            float mn    = fmaxf(m, v);
            float scale = __expf(m - mn);                // first edge: exp(-inf)=0
            float p     = __expf(v - mn);
            acc   = acc * scale + p * fa;
            denom = denom * scale + p;
            m = mn;
        }
    }
    out[n * 64 + lane] = (denom > 0.f ? acc / denom : 0.f) + bv;
}

// ============================================================================
extern "C" void kernel_launch(void* const* d_in, const int* in_sizes, int n_in,
                              void* d_out, int out_size, void* d_ws, size_t ws_size,
                              hipStream_t stream) {
    const float* x      = (const float*)d_in[0];
    const float* W      = (const float*)d_in[1];
    const float* attn_l = (const float*)d_in[2];
    const float* attn_r = (const float*)d_in[3];
    const float* bias   = (const float*)d_in[4];
    const int*   src    = (const int*)d_in[5];
    const int*   dst    = (const int*)d_in[6];
    float* out = (float*)d_out;

    // workspace layout (all 4B types, 16B-aligned ordering)
    float* feat     = (float*)d_ws;                          // N*64 f32 = 25.6 MB
    float* el       = feat + (size_t)N_NODES * 64;           // N*4
    float* er       = el   + (size_t)N_NODES * 4;            // N*4
    int*   cursor   = (int*)(er + (size_t)N_NODES * 4);      // N   (deg -> start -> end)
    int*   rowptr   = cursor + N_NODES;                      // N
    int*   edge_src = rowptr + N_NODES;                      // E = 6.4 MB
    int*   gtotal   = edge_src + N_EDGES;                    // 1

    k1_project<<<4096, 256, 0, stream>>>(x, W, attn_l, attn_r, feat, el, er, cursor, gtotal);
    k2_hist   <<<(N_EDGES / 4 + 255) / 256, 256, 0, stream>>>(dst, cursor);
    k3_segbase<<<(N_NODES + 255) / 256, 256, 0, stream>>>(cursor, rowptr, gtotal);
    k4_fill   <<<(N_EDGES / 4 + 255) / 256, 256, 0, stream>>>(src, dst, cursor, edge_src);
    k5_gather <<<(N_NODES * 64 + 255) / 256, 256, 0, stream>>>(rowptr, cursor, edge_src,
                                                               el, er, feat, bias, out);
}

// Round 9
// 468.097 us; speedup vs baseline: 1.0642x; 1.0642x over previous
//
#include <hip/hip_runtime.h>
#include <math.h>

#define N_NODES 100000
#define N_EDGES 1600000
#define NEG_SLOPE 0.2f
#define NPASS 4                      // fill passes; write region/pass = 1.6 MB < 4 MB L2

// ============================================================================
// k1: per-node projection feat = x @ W, attention logits el/er; zero the
//     degree counters and the global segment cursor.  One wave per node.
// ============================================================================
__global__ __launch_bounds__(256) void k1_project(
        const float* __restrict__ x, const float* __restrict__ W,
        const float* __restrict__ attn_l, const float* __restrict__ attn_r,
        float* __restrict__ feat, float* __restrict__ el, float* __restrict__ er,
        int* __restrict__ cursor, int* __restrict__ gtotal) {
    __shared__ float Ws[64 * 64];
    int t = threadIdx.x;
    for (int i = t; i < 1024; i += 256)                 // stage W (16 KB) via float4
        ((float4*)Ws)[i] = ((const float4*)W)[i];
    if (blockIdx.x == 0 && t == 0) *gtotal = 0;
    __syncthreads();

    int lane = t & 63;
    int wib  = t >> 6;                                  // wave in block, 0..3
    int h    = lane >> 4;
    float al = attn_l[lane];                            // attn_l is flat [4*16]
    float ar = attn_r[lane];
    int wavesTotal = (gridDim.x * blockDim.x) >> 6;

    for (int n = blockIdx.x * 4 + wib; n < N_NODES; n += wavesTotal) {
        float xv  = x[n * 64 + lane];
        float acc = 0.f;
        #pragma unroll
        for (int k = 0; k < 64; ++k) {
            float xk = __shfl(xv, k, 64);               // broadcast x[n][k]
            acc = fmaf(xk, Ws[k * 64 + lane], acc);
        }
        feat[n * 64 + lane] = acc;
        float vl = acc * al, vr = acc * ar;
        #pragma unroll
        for (int off = 8; off >= 1; off >>= 1) {        // reduce within 16-lane head group
            vl += __shfl_xor(vl, off, 64);
            vr += __shfl_xor(vr, off, 64);
        }
        if ((lane & 15) == 0) {
            el[n * 4 + h] = vl;
            er[n * 4 + h] = vr;
        }
        if (lane == 0) cursor[n] = 0;                   // zero degree counter
    }
}

// ============================================================================
// k2: degree histogram — cursor[d] = in-degree(d).
//     4 edges/thread via int4 (unchanged from round 8 — was not in top-5).
// ============================================================================
__global__ __launch_bounds__(256) void k2_hist(
        const int* __restrict__ dst, int* __restrict__ cursor) {
    int t = blockIdx.x * blockDim.x + threadIdx.x;
    if (t >= N_EDGES / 4) return;
    int4 d = ((const int4*)dst)[t];                     // 16B coalesced
    atomicAdd(&cursor[d.x], 1);
    atomicAdd(&cursor[d.y], 1);
    atomicAdd(&cursor[d.z], 1);
    atomicAdd(&cursor[d.w], 1);
}

// ============================================================================
// k3: assign each node a contiguous segment [start, start+deg).
//     Segment ORDER across nodes is irrelevant, so no full prefix scan:
//     wave-local prefix via shfl + ONE global atomicAdd per wave.
//     rowptr[n] = start; cursor[n] = start (becomes fill cursor).
// ============================================================================
__global__ __launch_bounds__(256) void k3_segbase(
        int* __restrict__ cursor, int* __restrict__ rowptr, int* __restrict__ gtotal) {
    int tid  = blockIdx.x * blockDim.x + threadIdx.x;
    int lane = threadIdx.x & 63;
    int n    = tid;
    int deg  = (n < N_NODES) ? cursor[n] : 0;
    // inclusive wave prefix sum
    int incl = deg;
    #pragma unroll
    for (int off = 1; off < 64; off <<= 1) {
        int v = __shfl_up(incl, off, 64);
        if (lane >= off) incl += v;
    }
    int waveTotal = __shfl(incl, 63, 64);
    int base = 0;
    if (lane == 63) base = atomicAdd(gtotal, waveTotal);
    base = __shfl(base, 63, 64);
    int start = base + incl - deg;                      // exclusive prefix
    if (n < N_NODES) {
        rowptr[n] = start;
        cursor[n] = start;
    }
}

// ============================================================================
// k4: phased fill — edge_src[pos] = src, pos = cursor[dst]++, but only for
//     dst in [lo, hi).  Round-8 post-mortem: k4 is write-eviction-throughput
//     bound (WRITE_SIZE 107 MB = 1.6M partial-line evictions @ ~850 GB/s).
//     Restricting each pass's write region to 1.6 MB (< 4 MB per-XCD L2)
//     lets dirty lines merge in L2 before eviction.  Scalar 1 edge/thread
//     (int4 MLP variant was a regression: occupancy 75%->42%).
// ============================================================================
__global__ __launch_bounds__(256) void k4_fill_phase(
        const int* __restrict__ src, const int* __restrict__ dst,
        int* __restrict__ cursor, int* __restrict__ edge_src,
        int lo, int hi) {
    int e = blockIdx.x * blockDim.x + threadIdx.x;
    if (e >= N_EDGES) return;
    int d = dst[e];
    if (d >= lo && d < hi) {
        int pos = atomicAdd(&cursor[d], 1);
        edge_src[pos] = src[e];
    }
}

// ============================================================================
// k5: gather-aggregate with online softmax.  One wave per dst node.
//     Lane f owns feature f (head h = f>>4).  After k4, cursor[n] == segment
//     end.  No atomics anywhere; epilogue (divide + bias) fused.
// ============================================================================
__global__ __launch_bounds__(256) void k5_gather(
        const int* __restrict__ rowptr, const int* __restrict__ cursor,
        const int* __restrict__ edge_src,
        const float* __restrict__ el, const float* __restrict__ er,
        const float* __restrict__ feat, const float* __restrict__ bias,
        float* __restrict__ out) {
    int lane = threadIdx.x & 63;
    int h    = lane >> 4;
    int n    = (blockIdx.x * blockDim.x + threadIdx.x) >> 6;   // wave id == node
    if (n >= N_NODES) return;

    int   row0 = rowptr[n];                              // broadcast loads
    int   row1 = cursor[n];
    float er_h = er[n * 4 + h];
    float bv   = bias[lane];

    float m = -INFINITY, denom = 0.f, acc = 0.f;
    for (int base = row0; base < row1; base += 64) {
        int nchunk = min(64, row1 - base);
        int sv = (base + lane < row1) ? edge_src[base + lane] : 0;  // coalesced
        for (int j = 0; j < nchunk; ++j) {
            int   s  = __shfl(sv, j, 64);
            float v  = el[s * 4 + h] + er_h;             // 16-lane broadcast load
            v = v > 0.f ? v : NEG_SLOPE * v;             // leaky relu
            float fa = feat[s * 64 + lane];              // coalesced 256B gather
            // online softmax update
            float mn    = fmaxf(m, v);
            float scale = __expf(m - mn);                // first edge: exp(-inf)=0
            float p     = __expf(v - mn);
            acc   = acc * scale + p * fa;
            denom = denom * scale + p;
            m = mn;
        }
    }
    out[n * 64 + lane] = (denom > 0.f ? acc / denom : 0.f) + bv;
}

// ============================================================================
extern "C" void kernel_launch(void* const* d_in, const int* in_sizes, int n_in,
                              void* d_out, int out_size, void* d_ws, size_t ws_size,
                              hipStream_t stream) {
    const float* x      = (const float*)d_in[0];
    const float* W      = (const float*)d_in[1];
    const float* attn_l = (const float*)d_in[2];
    const float* attn_r = (const float*)d_in[3];
    const float* bias   = (const float*)d_in[4];
    const int*   src    = (const int*)d_in[5];
    const int*   dst    = (const int*)d_in[6];
    float* out = (float*)d_out;

    // workspace layout (all 4B types, 16B-aligned ordering)
    float* feat     = (float*)d_ws;                          // N*64 f32 = 25.6 MB
    float* el       = feat + (size_t)N_NODES * 64;           // N*4
    float* er       = el   + (size_t)N_NODES * 4;            // N*4
    int*   cursor   = (int*)(er + (size_t)N_NODES * 4);      // N   (deg -> start -> end)
    int*   rowptr   = cursor + N_NODES;                      // N
    int*   edge_src = rowptr + N_NODES;                      // E = 6.4 MB
    int*   gtotal   = edge_src + N_EDGES;                    // 1

    k1_project<<<4096, 256, 0, stream>>>(x, W, attn_l, attn_r, feat, el, er, cursor, gtotal);
    k2_hist   <<<(N_EDGES / 4 + 255) / 256, 256, 0, stream>>>(dst, cursor);
    k3_segbase<<<(N_NODES + 255) / 256, 256, 0, stream>>>(cursor, rowptr, gtotal);
    const int nodesPerPass = (N_NODES + NPASS - 1) / NPASS;
    for (int p = 0; p < NPASS; ++p) {
        int lo = p * nodesPerPass;
        int hi = min(N_NODES, lo + nodesPerPass);
        k4_fill_phase<<<(N_EDGES + 255) / 256, 256, 0, stream>>>(src, dst, cursor,
                                                                 edge_src, lo, hi);
    }
    k5_gather <<<(N_NODES * 64 + 255) / 256, 256, 0, stream>>>(rowptr, cursor, edge_src,
                                                               el, er, feat, bias, out);
}

// Round 10
// 423.955 us; speedup vs baseline: 1.1750x; 1.1041x over previous
//
#include <hip/hip_runtime.h>
#include <math.h>

#define N_NODES 100000
#define N_EDGES 1600000
#define NEG_SLOPE 0.2f
#define NPASS 4                      // fill passes; write region/pass = 1.6 MB < 4 MB L2

// ============================================================================
// k1: per-node projection feat = x @ W, attention logits el/er; zero the
//     degree counters and the global segment cursor.  One wave per node.
// ============================================================================
__global__ __launch_bounds__(256) void k1_project(
        const float* __restrict__ x, const float* __restrict__ W,
        const float* __restrict__ attn_l, const float* __restrict__ attn_r,
        float* __restrict__ feat, float* __restrict__ el, float* __restrict__ er,
        int* __restrict__ cursor, int* __restrict__ gtotal) {
    __shared__ float Ws[64 * 64];
    int t = threadIdx.x;
    for (int i = t; i < 1024; i += 256)                 // stage W (16 KB) via float4
        ((float4*)Ws)[i] = ((const float4*)W)[i];
    if (blockIdx.x == 0 && t == 0) *gtotal = 0;
    __syncthreads();

    int lane = t & 63;
    int wib  = t >> 6;                                  // wave in block, 0..3
    int h    = lane >> 4;
    float al = attn_l[lane];                            // attn_l is flat [4*16]
    float ar = attn_r[lane];
    int wavesTotal = (gridDim.x * blockDim.x) >> 6;

    for (int n = blockIdx.x * 4 + wib; n < N_NODES; n += wavesTotal) {
        float xv  = x[n * 64 + lane];
        float acc = 0.f;
        #pragma unroll
        for (int k = 0; k < 64; ++k) {
            float xk = __shfl(xv, k, 64);               // broadcast x[n][k]
            acc = fmaf(xk, Ws[k * 64 + lane], acc);
        }
        feat[n * 64 + lane] = acc;
        float vl = acc * al, vr = acc * ar;
        #pragma unroll
        for (int off = 8; off >= 1; off >>= 1) {        // reduce within 16-lane head group
            vl += __shfl_xor(vl, off, 64);
            vr += __shfl_xor(vr, off, 64);
        }
        if ((lane & 15) == 0) {
            el[n * 4 + h] = vl;
            er[n * 4 + h] = vr;
        }
        if (lane == 0) cursor[n] = 0;                   // zero degree counter
    }
}

// ============================================================================
// k2: degree histogram — cursor[d] = in-degree(d).
//     4 edges/thread via int4 (not in top-5; unchanged).
// ============================================================================
__global__ __launch_bounds__(256) void k2_hist(
        const int* __restrict__ dst, int* __restrict__ cursor) {
    int t = blockIdx.x * blockDim.x + threadIdx.x;
    if (t >= N_EDGES / 4) return;
    int4 d = ((const int4*)dst)[t];                     // 16B coalesced
    atomicAdd(&cursor[d.x], 1);
    atomicAdd(&cursor[d.y], 1);
    atomicAdd(&cursor[d.z], 1);
    atomicAdd(&cursor[d.w], 1);
}

// ============================================================================
// k3: assign each node a contiguous segment [start, start+deg).
//     Wave-local prefix via shfl + ONE global atomicAdd per wave.
// ============================================================================
__global__ __launch_bounds__(256) void k3_segbase(
        int* __restrict__ cursor, int* __restrict__ rowptr, int* __restrict__ gtotal) {
    int tid  = blockIdx.x * blockDim.x + threadIdx.x;
    int lane = threadIdx.x & 63;
    int n    = tid;
    int deg  = (n < N_NODES) ? cursor[n] : 0;
    int incl = deg;
    #pragma unroll
    for (int off = 1; off < 64; off <<= 1) {
        int v = __shfl_up(incl, off, 64);
        if (lane >= off) incl += v;
    }
    int waveTotal = __shfl(incl, 63, 64);
    int base = 0;
    if (lane == 63) base = atomicAdd(gtotal, waveTotal);
    base = __shfl(base, 63, 64);
    int start = base + incl - deg;                      // exclusive prefix
    if (n < N_NODES) {
        rowptr[n] = start;
        cursor[n] = start;
    }
}

// ============================================================================
// k4: phased fill — dst in [lo,hi) only; write region/pass 1.6 MB fits L2 so
//     dirty lines merge before eviction (round-9 confirmed: k4 left top-5).
// ============================================================================
__global__ __launch_bounds__(256) void k4_fill_phase(
        const int* __restrict__ src, const int* __restrict__ dst,
        int* __restrict__ cursor, int* __restrict__ edge_src,
        int lo, int hi) {
    int e = blockIdx.x * blockDim.x + threadIdx.x;
    if (e >= N_EDGES) return;
    int d = dst[e];
    if (d >= lo && d < hi) {
        int pos = atomicAdd(&cursor[d], 1);
        edge_src[pos] = src[e];
    }
}

// ============================================================================
// k5: gather-aggregate, chunk-parallel softmax.  One wave per dst node.
//     Round-9 post-mortem: old per-edge serial chain (2 exps + rescale per
//     edge, redundant x64 lanes; 2 dependent gathers/iter, no pipelining) ->
//     VALUBusy 63% at only 27% HBM.
//     New layout per 16-edge chunk: lane (h*16+e) scores (edge e, head h) in
//     parallel (ONE exp instr / chunk), 4-step group-shfl max & sum, one
//     rescale per chunk.  Unrolled 16-wide fma loop puts 16 feat-gathers in
//     flight (readlane s_j -> sgpr base, bpermute p_j).
// ============================================================================
__global__ __launch_bounds__(256) void k5_gather(
        const int* __restrict__ rowptr, const int* __restrict__ cursor,
        const int* __restrict__ edge_src,
        const float* __restrict__ el, const float* __restrict__ er,
        const float* __restrict__ feat, const float* __restrict__ bias,
        float* __restrict__ out) {
    int lane = threadIdx.x & 63;
    int h    = lane >> 4;                                // head for score phase
    int e16  = lane & 15;                                // edge slot in chunk
    int n    = (blockIdx.x * blockDim.x + threadIdx.x) >> 6;   // wave id == node
    if (n >= N_NODES) return;

    int   row0 = rowptr[n];                              // broadcast loads
    int   row1 = cursor[n];
    float er_h = er[n * 4 + h];
    float bv   = bias[lane];
    int   pbase = lane & 48;                             // head-group base lane

    float m = -INFINITY, dnm = 0.f, acc = 0.f;
    for (int base = row0; base < row1; base += 16) {
        // ---- phase A: parallel scores for 16 edges x 4 heads ----
        int  ei    = base + e16;
        bool valid = ei < row1;
        int  s     = edge_src[valid ? ei : row0];        // clamp to a real edge
        float raw  = el[s * 4 + h] + er_h;               // 16B segment per edge
        raw = raw > 0.f ? raw : NEG_SLOPE * raw;         // leaky relu
        float sc = valid ? raw : -INFINITY;
        float cm = sc;                                   // chunk max (per head group)
        cm = fmaxf(cm, __shfl_xor(cm, 1, 64));
        cm = fmaxf(cm, __shfl_xor(cm, 2, 64));
        cm = fmaxf(cm, __shfl_xor(cm, 4, 64));
        cm = fmaxf(cm, __shfl_xor(cm, 8, 64));
        float mn = fmaxf(m, cm);
        float rs = __expf(m - mn);                       // chunk-level rescale
        float p  = __expf(sc - mn);                      // 0 for invalid lanes
        float ps = p;                                    // chunk denom sum
        ps += __shfl_xor(ps, 1, 64);
        ps += __shfl_xor(ps, 2, 64);
        ps += __shfl_xor(ps, 4, 64);
        ps += __shfl_xor(ps, 8, 64);
        dnm = dnm * rs + ps;
        acc *= rs;
        m = mn;
        // ---- phase B: 16 weighted feat rows, loads pipelined by unroll ----
        #pragma unroll
        for (int j = 0; j < 16; ++j) {
            float pj = __shfl(p, pbase + j, 64);         // p of (edge j, my head)
            int   sj = __shfl(s, j, 64);                 // uniform -> readlane
            float fa = feat[sj * 64 + lane];             // coalesced 256B row
            acc = fmaf(pj, fa, acc);                     // pj==0 for invalid j
        }
    }
    out[n * 64 + lane] = (dnm > 0.f ? acc / dnm : 0.f) + bv;
}

// ============================================================================
extern "C" void kernel_launch(void* const* d_in, const int* in_sizes, int n_in,
                              void* d_out, int out_size, void* d_ws, size_t ws_size,
                              hipStream_t stream) {
    const float* x      = (const float*)d_in[0];
    const float* W      = (const float*)d_in[1];
    const float* attn_l = (const float*)d_in[2];
    const float* attn_r = (const float*)d_in[3];
    const float* bias   = (const float*)d_in[4];
    const int*   src    = (const int*)d_in[5];
    const int*   dst    = (const int*)d_in[6];
    float* out = (float*)d_out;

    // workspace layout (all 4B types, 16B-aligned ordering)
    float* feat     = (float*)d_ws;                          // N*64 f32 = 25.6 MB
    float* el       = feat + (size_t)N_NODES * 64;           // N*4
    float* er       = el   + (size_t)N_NODES * 4;            // N*4
    int*   cursor   = (int*)(er + (size_t)N_NODES * 4);      // N   (deg -> start -> end)
    int*   rowptr   = cursor + N_NODES;                      // N
    int*   edge_src = rowptr + N_NODES;                      // E = 6.4 MB
    int*   gtotal   = edge_src + N_EDGES;                    // 1

    k1_project<<<4096, 256, 0, stream>>>(x, W, attn_l, attn_r, feat, el, er, cursor, gtotal);
    k2_hist   <<<(N_EDGES / 4 + 255) / 256, 256, 0, stream>>>(dst, cursor);
    k3_segbase<<<(N_NODES + 255) / 256, 256, 0, stream>>>(cursor, rowptr, gtotal);
    const int nodesPerPass = (N_NODES + NPASS - 1) / NPASS;
    for (int p = 0; p < NPASS; ++p) {
        int lo = p * nodesPerPass;
        int hi = min(N_NODES, lo + nodesPerPass);
        k4_fill_phase<<<(N_EDGES + 255) / 256, 256, 0, stream>>>(src, dst, cursor,
                                                                 edge_src, lo, hi);
    }
    k5_gather <<<(N_NODES * 64 + 255) / 256, 256, 0, stream>>>(rowptr, cursor, edge_src,
                                                               el, er, feat, bias, out);
}

// Round 11
// 370.101 us; speedup vs baseline: 1.3460x; 1.1455x over previous
//
#include <hip/hip_runtime.h>
#include <math.h>

#define N_NODES 100000
#define N_EDGES 1600000
#define NEG_SLOPE 0.2f
#define NPASS 4                      // fill passes; write region/pass = 1.6 MB < 4 MB L2

// ============================================================================
// k1: per-node projection feat = x @ W, attention logits el/er; zero the
//     degree counters and the global segment cursor.
//     Round-10 post-mortem: old version was 64x {shfl -> dependent fma} per
//     node = wave-serial DS chain (VALUBusy 20%, 96 us).  New version: thread
//     owns output col `lane`, W column lives in 64 VGPRs (loaded once);
//     x[n][*] is wave-uniform -> 16 broadcast float4 loads/node (no DS at
//     all); 4 independent fma chains for ILP.
// ============================================================================
__global__ __launch_bounds__(256) void k1_project(
        const float* __restrict__ x, const float* __restrict__ W,
        const float* __restrict__ attn_l, const float* __restrict__ attn_r,
        float* __restrict__ feat, float* __restrict__ el, float* __restrict__ er,
        int* __restrict__ cursor, int* __restrict__ gtotal) {
    int t    = threadIdx.x;
    int lane = t & 63;
    int wib  = t >> 6;                                  // wave in block, 0..3
    int h    = lane >> 4;
    if (blockIdx.x == 0 && t == 0) *gtotal = 0;

    float w[64];                                        // W[:, lane] in VGPRs
    #pragma unroll
    for (int k = 0; k < 64; ++k) w[k] = W[k * 64 + lane];   // coalesced per k

    float al = attn_l[lane];                            // attn_l is flat [4*16]
    float ar = attn_r[lane];
    int wavesTotal = (gridDim.x * blockDim.x) >> 6;

    for (int n = blockIdx.x * 4 + wib; n < N_NODES; n += wavesTotal) {
        int nu = __builtin_amdgcn_readfirstlane(n);     // force wave-uniform base
        const float4* xr = (const float4*)(x + (size_t)nu * 64);
        float a0 = 0.f, a1 = 0.f, a2 = 0.f, a3 = 0.f;   // 4 independent chains
        #pragma unroll
        for (int kq = 0; kq < 16; ++kq) {
            float4 xq = xr[kq];                         // uniform addr -> broadcast
            a0 = fmaf(xq.x, w[4 * kq + 0], a0);
            a1 = fmaf(xq.y, w[4 * kq + 1], a1);
            a2 = fmaf(xq.z, w[4 * kq + 2], a2);
            a3 = fmaf(xq.w, w[4 * kq + 3], a3);
        }
        float acc = (a0 + a1) + (a2 + a3);
        feat[n * 64 + lane] = acc;
        float vl = acc * al, vr = acc * ar;
        #pragma unroll
        for (int off = 8; off >= 1; off >>= 1) {        // reduce within 16-lane head group
            vl += __shfl_xor(vl, off, 64);
            vr += __shfl_xor(vr, off, 64);
        }
        if ((lane & 15) == 0) {
            el[n * 4 + h] = vl;
            er[n * 4 + h] = vr;
        }
        if (lane == 0) cursor[n] = 0;                   // zero degree counter
    }
}

// ============================================================================
// k2: degree histogram — cursor[d] = in-degree(d).
//     4 edges/thread via int4 (not in top-5; unchanged).
// ============================================================================
__global__ __launch_bounds__(256) void k2_hist(
        const int* __restrict__ dst, int* __restrict__ cursor) {
    int t = blockIdx.x * blockDim.x + threadIdx.x;
    if (t >= N_EDGES / 4) return;
    int4 d = ((const int4*)dst)[t];                     // 16B coalesced
    atomicAdd(&cursor[d.x], 1);
    atomicAdd(&cursor[d.y], 1);
    atomicAdd(&cursor[d.z], 1);
    atomicAdd(&cursor[d.w], 1);
}

// ============================================================================
// k3: assign each node a contiguous segment [start, start+deg).
//     Wave-local prefix via shfl + ONE global atomicAdd per wave.
// ============================================================================
__global__ __launch_bounds__(256) void k3_segbase(
        int* __restrict__ cursor, int* __restrict__ rowptr, int* __restrict__ gtotal) {
    int tid  = blockIdx.x * blockDim.x + threadIdx.x;
    int lane = threadIdx.x & 63;
    int n    = tid;
    int deg  = (n < N_NODES) ? cursor[n] : 0;
    int incl = deg;
    #pragma unroll
    for (int off = 1; off < 64; off <<= 1) {
        int v = __shfl_up(incl, off, 64);
        if (lane >= off) incl += v;
    }
    int waveTotal = __shfl(incl, 63, 64);
    int base = 0;
    if (lane == 63) base = atomicAdd(gtotal, waveTotal);
    base = __shfl(base, 63, 64);
    int start = base + incl - deg;                      // exclusive prefix
    if (n < N_NODES) {
        rowptr[n] = start;
        cursor[n] = start;
    }
}

// ============================================================================
// k4: phased fill — dst in [lo,hi) only; write region/pass 1.6 MB fits L2 so
//     dirty lines merge before eviction (round-9 confirmed: k4 left top-5).
// ============================================================================
__global__ __launch_bounds__(256) void k4_fill_phase(
        const int* __restrict__ src, const int* __restrict__ dst,
        int* __restrict__ cursor, int* __restrict__ edge_src,
        int lo, int hi) {
    int e = blockIdx.x * blockDim.x + threadIdx.x;
    if (e >= N_EDGES) return;
    int d = dst[e];
    if (d >= lo && d < hi) {
        int pos = atomicAdd(&cursor[d], 1);
        edge_src[pos] = src[e];
    }
}

// ============================================================================
// k5: gather-aggregate, chunk-parallel softmax.  One wave per dst node.
//     (round-10 confirmed: 121 -> ~77 us; unchanged this round)
// ============================================================================
__global__ __launch_bounds__(256) void k5_gather(
        const int* __restrict__ rowptr, const int* __restrict__ cursor,
        const int* __restrict__ edge_src,
        const float* __restrict__ el, const float* __restrict__ er,
        const float* __restrict__ feat, const float* __restrict__ bias,
        float* __restrict__ out) {
    int lane = threadIdx.x & 63;
    int h    = lane >> 4;                                // head for score phase
    int e16  = lane & 15;                                // edge slot in chunk
    int n    = (blockIdx.x * blockDim.x + threadIdx.x) >> 6;   // wave id == node
    if (n >= N_NODES) return;

    int   row0 = rowptr[n];                              // broadcast loads
    int   row1 = cursor[n];
    float er_h = er[n * 4 + h];
    float bv   = bias[lane];
    int   pbase = lane & 48;                             // head-group base lane

    float m = -INFINITY, dnm = 0.f, acc = 0.f;
    for (int base = row0; base < row1; base += 16) {
        // ---- phase A: parallel scores for 16 edges x 4 heads ----
        int  ei    = base + e16;
        bool valid = ei < row1;
        int  s     = edge_src[valid ? ei : row0];        // clamp to a real edge
        float raw  = el[s * 4 + h] + er_h;               // 16B segment per edge
        raw = raw > 0.f ? raw : NEG_SLOPE * raw;         // leaky relu
        float sc = valid ? raw : -INFINITY;
        float cm = sc;                                   // chunk max (per head group)
        cm = fmaxf(cm, __shfl_xor(cm, 1, 64));
        cm = fmaxf(cm, __shfl_xor(cm, 2, 64));
        cm = fmaxf(cm, __shfl_xor(cm, 4, 64));
        cm = fmaxf(cm, __shfl_xor(cm, 8, 64));
        float mn = fmaxf(m, cm);
        float rs = __expf(m - mn);                       // chunk-level rescale
        float p  = __expf(sc - mn);                      // 0 for invalid lanes
        float ps = p;                                    // chunk denom sum
        ps += __shfl_xor(ps, 1, 64);
        ps += __shfl_xor(ps, 2, 64);
        ps += __shfl_xor(ps, 4, 64);
        ps += __shfl_xor(ps, 8, 64);
        dnm = dnm * rs + ps;
        acc *= rs;
        m = mn;
        // ---- phase B: 16 weighted feat rows, loads pipelined by unroll ----
        #pragma unroll
        for (int j = 0; j < 16; ++j) {
            float pj = __shfl(p, pbase + j, 64);         // p of (edge j, my head)
            int   sj = __shfl(s, j, 64);                 // uniform -> readlane
            float fa = feat[sj * 64 + lane];             // coalesced 256B row
            acc = fmaf(pj, fa, acc);                     // pj==0 for invalid j
        }
    }
    out[n * 64 + lane] = (dnm > 0.f ? acc / dnm : 0.f) + bv;
}

// ============================================================================
extern "C" void kernel_launch(void* const* d_in, const int* in_sizes, int n_in,
                              void* d_out, int out_size, void* d_ws, size_t ws_size,
                              hipStream_t stream) {
    const float* x      = (const float*)d_in[0];
    const float* W      = (const float*)d_in[1];
    const float* attn_l = (const float*)d_in[2];
    const float* attn_r = (const float*)d_in[3];
    const float* bias   = (const float*)d_in[4];
    const int*   src    = (const int*)d_in[5];
    const int*   dst    = (const int*)d_in[6];
    float* out = (float*)d_out;

    // workspace layout (all 4B types, 16B-aligned ordering)
    float* feat     = (float*)d_ws;                          // N*64 f32 = 25.6 MB
    float* el       = feat + (size_t)N_NODES * 64;           // N*4
    float* er       = el   + (size_t)N_NODES * 4;            // N*4
    int*   cursor   = (int*)(er + (size_t)N_NODES * 4);      // N   (deg -> start -> end)
    int*   rowptr   = cursor + N_NODES;                      // N
    int*   edge_src = rowptr + N_NODES;                      // E = 6.4 MB
    int*   gtotal   = edge_src + N_EDGES;                    // 1

    k1_project<<<2048, 256, 0, stream>>>(x, W, attn_l, attn_r, feat, el, er, cursor, gtotal);
    k2_hist   <<<(N_EDGES / 4 + 255) / 256, 256, 0, stream>>>(dst, cursor);
    k3_segbase<<<(N_NODES + 255) / 256, 256, 0, stream>>>(cursor, rowptr, gtotal);
    const int nodesPerPass = (N_NODES + NPASS - 1) / NPASS;
    for (int p = 0; p < NPASS; ++p) {
        int lo = p * nodesPerPass;
        int hi = min(N_NODES, lo + nodesPerPass);
        k4_fill_phase<<<(N_EDGES + 255) / 256, 256, 0, stream>>>(src, dst, cursor,
                                                                 edge_src, lo, hi);
    }
    k5_gather <<<(N_NODES * 64 + 255) / 256, 256, 0, stream>>>(rowptr, cursor, edge_src,
                                                               el, er, feat, bias, out);
}

// Round 12
// 352.670 us; speedup vs baseline: 1.4125x; 1.0494x over previous
//
#include <hip/hip_runtime.h>
#include <math.h>

#define N_NODES 100000
#define N_EDGES 1600000
#define NEG_SLOPE 0.2f
#define NPASS 2                      // fill passes; write region/pass = 3.2 MB < 4 MB L2

// ============================================================================
// k1: per-node projection feat = x @ W (thread owns col, W in VGPRs, x via
//     wave-uniform broadcast float4 loads), logits el/er, zero deg counters.
//     (round-11 confirmed: 96 -> ~42 us; unchanged)
// ============================================================================
__global__ __launch_bounds__(256) void k1_project(
        const float* __restrict__ x, const float* __restrict__ W,
        const float* __restrict__ attn_l, const float* __restrict__ attn_r,
        float* __restrict__ feat, float* __restrict__ el, float* __restrict__ er,
        int* __restrict__ deg, int* __restrict__ gtotal) {
    int t    = threadIdx.x;
    int lane = t & 63;
    int wib  = t >> 6;                                  // wave in block, 0..3
    int h    = lane >> 4;
    if (blockIdx.x == 0 && t == 0) *gtotal = 0;

    float w[64];                                        // W[:, lane] in VGPRs
    #pragma unroll
    for (int k = 0; k < 64; ++k) w[k] = W[k * 64 + lane];   // coalesced per k

    float al = attn_l[lane];                            // attn_l is flat [4*16]
    float ar = attn_r[lane];
    int wavesTotal = (gridDim.x * blockDim.x) >> 6;

    for (int n = blockIdx.x * 4 + wib; n < N_NODES; n += wavesTotal) {
        int nu = __builtin_amdgcn_readfirstlane(n);     // force wave-uniform base
        const float4* xr = (const float4*)(x + (size_t)nu * 64);
        float a0 = 0.f, a1 = 0.f, a2 = 0.f, a3 = 0.f;   // 4 independent chains
        #pragma unroll
        for (int kq = 0; kq < 16; ++kq) {
            float4 xq = xr[kq];                         // uniform addr -> broadcast
            a0 = fmaf(xq.x, w[4 * kq + 0], a0);
            a1 = fmaf(xq.y, w[4 * kq + 1], a1);
            a2 = fmaf(xq.z, w[4 * kq + 2], a2);
            a3 = fmaf(xq.w, w[4 * kq + 3], a3);
        }
        float acc = (a0 + a1) + (a2 + a3);
        feat[n * 64 + lane] = acc;
        float vl = acc * al, vr = acc * ar;
        #pragma unroll
        for (int off = 8; off >= 1; off >>= 1) {        // reduce within 16-lane head group
            vl += __shfl_xor(vl, off, 64);
            vr += __shfl_xor(vr, off, 64);
        }
        if ((lane & 15) == 0) {
            el[n * 4 + h] = vl;
            er[n * 4 + h] = vr;
        }
        if (lane == 0) deg[n] = 0;                      // zero degree counter
    }
}

// ============================================================================
// k2: histogram + RANK RECORDING.  rank[e] = this edge's slot within its dst
//     segment (the atomicAdd return).  rank is written COALESCED (int4) into
//     d_out's first 6.4 MB (dead scratch until k5 overwrites all of out).
//     This makes the fill pass atomic-free.
// ============================================================================
__global__ __launch_bounds__(256) void k2_hist_rank(
        const int* __restrict__ dst, int* __restrict__ deg, int* __restrict__ rank) {
    int t = blockIdx.x * blockDim.x + threadIdx.x;
    if (t >= N_EDGES / 4) return;
    int4 d = ((const int4*)dst)[t];                     // 16B coalesced
    int4 r;
    r.x = atomicAdd(&deg[d.x], 1);
    r.y = atomicAdd(&deg[d.y], 1);
    r.z = atomicAdd(&deg[d.z], 1);
    r.w = atomicAdd(&deg[d.w], 1);
    ((int4*)rank)[t] = r;                               // coalesced 16B store
}

// ============================================================================
// k3: rowptr[n] = exclusive prefix of deg (segment order irrelevant ->
//     wave-local shfl prefix + ONE global atomicAdd per wave).  deg is kept
//     intact (k5 needs it for segment end).
// ============================================================================
__global__ __launch_bounds__(256) void k3_segbase(
        const int* __restrict__ deg, int* __restrict__ rowptr, int* __restrict__ gtotal) {
    int tid  = blockIdx.x * blockDim.x + threadIdx.x;
    int lane = threadIdx.x & 63;
    int n    = tid;
    int dg   = (n < N_NODES) ? deg[n] : 0;
    int incl = dg;
    #pragma unroll
    for (int off = 1; off < 64; off <<= 1) {
        int v = __shfl_up(incl, off, 64);
        if (lane >= off) incl += v;
    }
    int waveTotal = __shfl(incl, 63, 64);
    int base = 0;
    if (lane == 63) base = atomicAdd(gtotal, waveTotal);
    base = __shfl(base, 63, 64);
    if (n < N_NODES) rowptr[n] = base + incl - dg;      // exclusive prefix
}

// ============================================================================
// k4: ATOMIC-FREE phased fill — pos = rowptr[d] + rank[e]; only dst in
//     [lo,hi) written per pass so the 3.2 MB write region L2-merges before
//     eviction (round-9 confirmed the eviction model).  int4 loads + 4
//     independent scatter chains (safe now: no atomic serialization).
// ============================================================================
__global__ __launch_bounds__(256) void k4_fill_phase(
        const int* __restrict__ src, const int* __restrict__ dst,
        const int* __restrict__ rank, const int* __restrict__ rowptr,
        int* __restrict__ edge_src, int lo, int hi) {
    int t = blockIdx.x * blockDim.x + threadIdx.x;
    if (t >= N_EDGES / 4) return;
    int4 d = ((const int4*)dst)[t];                     // 16B coalesced
    int4 s = ((const int4*)src)[t];
    int4 r = ((const int4*)rank)[t];
    if (d.x >= lo && d.x < hi) edge_src[rowptr[d.x] + r.x] = s.x;
    if (d.y >= lo && d.y < hi) edge_src[rowptr[d.y] + r.y] = s.y;
    if (d.z >= lo && d.z < hi) edge_src[rowptr[d.z] + r.z] = s.z;
    if (d.w >= lo && d.w < hi) edge_src[rowptr[d.w] + r.w] = s.w;
}

// ============================================================================
// k5: gather-aggregate, chunk-parallel softmax.  One wave per dst node.
//     NEW: wave-uniform early break in phase B — Poisson(16) degrees made the
//     fixed 16-iteration tail waste ~50% of gather traffic (round-11 FETCH
//     229 MB vs ~160 ideal).  nvalid is wave-uniform -> scalar branch.
// ============================================================================
__global__ __launch_bounds__(256) void k5_gather(
        const int* __restrict__ rowptr, const int* __restrict__ deg,
        const int* __restrict__ edge_src,
        const float* __restrict__ el, const float* __restrict__ er,
        const float* __restrict__ feat, const float* __restrict__ bias,
        float* __restrict__ out) {
    int lane = threadIdx.x & 63;
    int h    = lane >> 4;                                // head for score phase
    int e16  = lane & 15;                                // edge slot in chunk
    int n    = (blockIdx.x * blockDim.x + threadIdx.x) >> 6;   // wave id == node
    if (n >= N_NODES) return;

    int   row0 = rowptr[n];                              // broadcast loads
    int   row1 = row0 + deg[n];
    float er_h = er[n * 4 + h];
    float bv   = bias[lane];
    int   pbase = lane & 48;                             // head-group base lane

    float m = -INFINITY, dnm = 0.f, acc = 0.f;
    for (int base = row0; base < row1; base += 16) {
        int nvalid = min(16, row1 - base);               // wave-uniform
        // ---- phase A: parallel scores for 16 edges x 4 heads ----
        bool valid = e16 < nvalid;
        int  s     = edge_src[valid ? base + e16 : row0];   // clamp to a real edge
        float raw  = el[s * 4 + h] + er_h;               // 16B segment per edge
        raw = raw > 0.f ? raw : NEG_SLOPE * raw;         // leaky relu
        float sc = valid ? raw : -INFINITY;
        float cm = sc;                                   // chunk max (per head group)
        cm = fmaxf(cm, __shfl_xor(cm, 1, 64));
        cm = fmaxf(cm, __shfl_xor(cm, 2, 64));
        cm = fmaxf(cm, __shfl_xor(cm, 4, 64));
        cm = fmaxf(cm, __shfl_xor(cm, 8, 64));
        float mn = fmaxf(m, cm);
        float rs = __expf(m - mn);                       // chunk-level rescale
        float p  = __expf(sc - mn);                      // 0 for invalid lanes
        float ps = p;                                    // chunk denom sum
        ps += __shfl_xor(ps, 1, 64);
        ps += __shfl_xor(ps, 2, 64);
        ps += __shfl_xor(ps, 4, 64);
        ps += __shfl_xor(ps, 8, 64);
        dnm = dnm * rs + ps;
        acc *= rs;
        m = mn;
        // ---- phase B: weighted feat rows; early break is wave-uniform ----
        #pragma unroll
        for (int j = 0; j < 16; ++j) {
            if (j >= nvalid) break;                      // scalar branch, no pad gathers
            float pj = __shfl(p, pbase + j, 64);         // p of (edge j, my head)
            int   sj = __shfl(s, j, 64);                 // uniform -> readlane
            float fa = feat[sj * 64 + lane];             // coalesced 256B row
            acc = fmaf(pj, fa, acc);
        }
    }
    out[n * 64 + lane] = (dnm > 0.f ? acc / dnm : 0.f) + bv;
}

// ============================================================================
extern "C" void kernel_launch(void* const* d_in, const int* in_sizes, int n_in,
                              void* d_out, int out_size, void* d_ws, size_t ws_size,
                              hipStream_t stream) {
    const float* x      = (const float*)d_in[0];
    const float* W      = (const float*)d_in[1];
    const float* attn_l = (const float*)d_in[2];
    const float* attn_r = (const float*)d_in[3];
    const float* bias   = (const float*)d_in[4];
    const int*   src    = (const int*)d_in[5];
    const int*   dst    = (const int*)d_in[6];
    float* out = (float*)d_out;

    // workspace layout
    float* feat     = (float*)d_ws;                          // N*64 f32 = 25.6 MB
    float* el       = feat + (size_t)N_NODES * 64;           // N*4
    float* er       = el   + (size_t)N_NODES * 4;            // N*4
    int*   deg      = (int*)(er + (size_t)N_NODES * 4);      // N
    int*   rowptr   = deg + N_NODES;                         // N
    int*   edge_src = rowptr + N_NODES;                      // E = 6.4 MB
    int*   gtotal   = edge_src + N_EDGES;                    // 1
    // rank lives in d_out's first 6.4 MB: dead scratch until k5 overwrites
    // every element of out (wave per node writes all 64 lanes).
    int*   rank     = (int*)d_out;                           // E

    k1_project<<<2048, 256, 0, stream>>>(x, W, attn_l, attn_r, feat, el, er, deg, gtotal);
    k2_hist_rank<<<(N_EDGES / 4 + 255) / 256, 256, 0, stream>>>(dst, deg, rank);
    k3_segbase<<<(N_NODES + 255) / 256, 256, 0, stream>>>(deg, rowptr, gtotal);
    const int nodesPerPass = (N_NODES + NPASS - 1) / NPASS;
    for (int p = 0; p < NPASS; ++p) {
        int lo = p * nodesPerPass;
        int hi = min(N_NODES, lo + nodesPerPass);
        k4_fill_phase<<<(N_EDGES / 4 + 255) / 256, 256, 0, stream>>>(src, dst, rank,
                                                                     rowptr, edge_src, lo, hi);
    }
    k5_gather<<<(N_NODES * 64 + 255) / 256, 256, 0, stream>>>(rowptr, deg, edge_src,
                                                              el, er, feat, bias, out);
}

// Round 15
// 305.593 us; speedup vs baseline: 1.6301x; 1.1541x over previous
//
#include <hip/hip_runtime.h>
#include <math.h>

#define N_NODES 100000
#define N_EDGES 1600000
#define NEG_SLOPE 0.2f
#define NPASS 2                      // fill passes; write region/pass = 3.2 MB < 4 MB L2

// ============================================================================
// k1: per-node projection feat = x @ W (thread owns col, W in VGPRs, x via
//     wave-uniform broadcast float4 loads), logits el/er, zero deg counters.
//     (round-11 confirmed: 96 -> ~42 us; unchanged)
// ============================================================================
__global__ __launch_bounds__(256) void k1_project(
        const float* __restrict__ x, const float* __restrict__ W,
        const float* __restrict__ attn_l, const float* __restrict__ attn_r,
        float* __restrict__ feat, float* __restrict__ el, float* __restrict__ er,
        int* __restrict__ deg, int* __restrict__ gtotal) {
    int t    = threadIdx.x;
    int lane = t & 63;
    int wib  = t >> 6;                                  // wave in block, 0..3
    int h    = lane >> 4;
    if (blockIdx.x == 0 && t == 0) *gtotal = 0;

    float w[64];                                        // W[:, lane] in VGPRs
    #pragma unroll
    for (int k = 0; k < 64; ++k) w[k] = W[k * 64 + lane];   // coalesced per k

    float al = attn_l[lane];                            // attn_l is flat [4*16]
    float ar = attn_r[lane];
    int wavesTotal = (gridDim.x * blockDim.x) >> 6;

    for (int n = blockIdx.x * 4 + wib; n < N_NODES; n += wavesTotal) {
        int nu = __builtin_amdgcn_readfirstlane(n);     // force wave-uniform base
        const float4* xr = (const float4*)(x + (size_t)nu * 64);
        float a0 = 0.f, a1 = 0.f, a2 = 0.f, a3 = 0.f;   // 4 independent chains
        #pragma unroll
        for (int kq = 0; kq < 16; ++kq) {
            float4 xq = xr[kq];                         // uniform addr -> broadcast
            a0 = fmaf(xq.x, w[4 * kq + 0], a0);
            a1 = fmaf(xq.y, w[4 * kq + 1], a1);
            a2 = fmaf(xq.z, w[4 * kq + 2], a2);
            a3 = fmaf(xq.w, w[4 * kq + 3], a3);
        }
        float acc = (a0 + a1) + (a2 + a3);
        feat[n * 64 + lane] = acc;
        float vl = acc * al, vr = acc * ar;
        #pragma unroll
        for (int off = 8; off >= 1; off >>= 1) {        // reduce within 16-lane head group
            vl += __shfl_xor(vl, off, 64);
            vr += __shfl_xor(vr, off, 64);
        }
        if ((lane & 15) == 0) {
            el[n * 4 + h] = vl;
            er[n * 4 + h] = vr;
        }
        if (lane == 0) deg[n] = 0;                      // zero degree counter
    }
}

// ============================================================================
// k2: histogram + RANK RECORDING.  rank[e] = this edge's slot within its dst
//     segment (the atomicAdd return).  rank is written COALESCED (int4) into
//     d_out's first 6.4 MB (dead scratch until k5 overwrites all of out).
//     This makes the fill pass atomic-free.  (round-12 confirmed)
// ============================================================================
__global__ __launch_bounds__(256) void k2_hist_rank(
        const int* __restrict__ dst, int* __restrict__ deg, int* __restrict__ rank) {
    int t = blockIdx.x * blockDim.x + threadIdx.x;
    if (t >= N_EDGES / 4) return;
    int4 d = ((const int4*)dst)[t];                     // 16B coalesced
    int4 r;
    r.x = atomicAdd(&deg[d.x], 1);
    r.y = atomicAdd(&deg[d.y], 1);
    r.z = atomicAdd(&deg[d.z], 1);
    r.w = atomicAdd(&deg[d.w], 1);
    ((int4*)rank)[t] = r;                               // coalesced 16B store
}

// ============================================================================
// k3: rowptr[n] = exclusive prefix of deg (segment order irrelevant ->
//     wave-local shfl prefix + ONE global atomicAdd per wave).  deg is kept
//     intact (k5 needs it for segment end).
// ============================================================================
__global__ __launch_bounds__(256) void k3_segbase(
        const int* __restrict__ deg, int* __restrict__ rowptr, int* __restrict__ gtotal) {
    int tid  = blockIdx.x * blockDim.x + threadIdx.x;
    int lane = threadIdx.x & 63;
    int n    = tid;
    int dg   = (n < N_NODES) ? deg[n] : 0;
    int incl = dg;
    #pragma unroll
    for (int off = 1; off < 64; off <<= 1) {
        int v = __shfl_up(incl, off, 64);
        if (lane >= off) incl += v;
    }
    int waveTotal = __shfl(incl, 63, 64);
    int base = 0;
    if (lane == 63) base = atomicAdd(gtotal, waveTotal);
    base = __shfl(base, 63, 64);
    if (n < N_NODES) rowptr[n] = base + incl - dg;      // exclusive prefix
}

// ============================================================================
// k4: ATOMIC-FREE phased fill — pos = rowptr[d] + rank[e]; only dst in
//     [lo,hi) written per pass so the 3.2 MB write region L2-merges before
//     eviction.  int4 loads + 4 independent scatter chains.  (round-12
//     confirmed: build chain ~70 us faster than atomic fill @ NPASS=4)
// ============================================================================
__global__ __launch_bounds__(256) void k4_fill_phase(
        const int* __restrict__ src, const int* __restrict__ dst,
        const int* __restrict__ rank, const int* __restrict__ rowptr,
        int* __restrict__ edge_src, int lo, int hi) {
    int t = blockIdx.x * blockDim.x + threadIdx.x;
    if (t >= N_EDGES / 4) return;
    int4 d = ((const int4*)dst)[t];                     // 16B coalesced
    int4 s = ((const int4*)src)[t];
    int4 r = ((const int4*)rank)[t];
    if (d.x >= lo && d.x < hi) edge_src[rowptr[d.x] + r.x] = s.x;
    if (d.y >= lo && d.y < hi) edge_src[rowptr[d.y] + r.y] = s.y;
    if (d.z >= lo && d.z < hi) edge_src[rowptr[d.z] + r.z] = s.z;
    if (d.w >= lo && d.w < hi) edge_src[rowptr[d.w] + r.w] = s.w;
}

// ============================================================================
// k5: gather-aggregate, chunk-parallel softmax.  One wave per dst node.
//     Round-12 post-mortem: the nvalid early-break REGRESSED 73->125 us —
//     a data-dependent break inside the unroll made every feat load control-
//     dependent (no 16-deep load pipelining), while the "wasted" padded
//     gathers were L1/L2 hits all along (FETCH unchanged 229 vs 230 MB).
//     Reverted to fixed 16 iterations (round-11 form, measured 73 us).
// ============================================================================
__global__ __launch_bounds__(256) void k5_gather(
        const int* __restrict__ rowptr, const int* __restrict__ deg,
        const int* __restrict__ edge_src,
        const float* __restrict__ el, const float* __restrict__ er,
        const float* __restrict__ feat, const float* __restrict__ bias,
        float* __restrict__ out) {
    int lane = threadIdx.x & 63;
    int h    = lane >> 4;                                // head for score phase
    int e16  = lane & 15;                                // edge slot in chunk
    int n    = (blockIdx.x * blockDim.x + threadIdx.x) >> 6;   // wave id == node
    if (n >= N_NODES) return;

    int   row0 = rowptr[n];                              // broadcast loads
    int   row1 = row0 + deg[n];
    float er_h = er[n * 4 + h];
    float bv   = bias[lane];
    int   pbase = lane & 48;                             // head-group base lane

    float m = -INFINITY, dnm = 0.f, acc = 0.f;
    for (int base = row0; base < row1; base += 16) {
        // ---- phase A: parallel scores for 16 edges x 4 heads ----
        int  ei    = base + e16;
        bool valid = ei < row1;
        int  s     = edge_src[valid ? ei : row0];        // clamp to a real edge
        float raw  = el[s * 4 + h] + er_h;               // 16B segment per edge
        raw = raw > 0.f ? raw : NEG_SLOPE * raw;         // leaky relu
        float sc = valid ? raw : -INFINITY;
        float cm = sc;                                   // chunk max (per head group)
        cm = fmaxf(cm, __shfl_xor(cm, 1, 64));
        cm = fmaxf(cm, __shfl_xor(cm, 2, 64));
        cm = fmaxf(cm, __shfl_xor(cm, 4, 64));
        cm = fmaxf(cm, __shfl_xor(cm, 8, 64));
        float mn = fmaxf(m, cm);
        float rs = __expf(m - mn);                       // chunk-level rescale
        float p  = __expf(sc - mn);                      // 0 for invalid lanes
        float ps = p;                                    // chunk denom sum
        ps += __shfl_xor(ps, 1, 64);
        ps += __shfl_xor(ps, 2, 64);
        ps += __shfl_xor(ps, 4, 64);
        ps += __shfl_xor(ps, 8, 64);
        dnm = dnm * rs + ps;
        acc *= rs;
        m = mn;
        // ---- phase B: 16 weighted feat rows, fixed trip count so all 16
        //      gathers pipeline; padded j's re-read a cached row (free) ----
        #pragma unroll
        for (int j = 0; j < 16; ++j) {
            float pj = __shfl(p, pbase + j, 64);         // p of (edge j, my head)
            int   sj = __shfl(s, j, 64);                 // uniform -> readlane
            float fa = feat[sj * 64 + lane];             // coalesced 256B row
            acc = fmaf(pj, fa, acc);                     // pj==0 for invalid j
        }
    }
    out[n * 64 + lane] = (dnm > 0.f ? acc / dnm : 0.f) + bv;
}

// ============================================================================
extern "C" void kernel_launch(void* const* d_in, const int* in_sizes, int n_in,
                              void* d_out, int out_size, void* d_ws, size_t ws_size,
                              hipStream_t stream) {
    const float* x      = (const float*)d_in[0];
    const float* W      = (const float*)d_in[1];
    const float* attn_l = (const float*)d_in[2];
    const float* attn_r = (const float*)d_in[3];
    const float* bias   = (const float*)d_in[4];
    const int*   src    = (const int*)d_in[5];
    const int*   dst    = (const int*)d_in[6];
    float* out = (float*)d_out;

    // workspace layout
    float* feat     = (float*)d_ws;                          // N*64 f32 = 25.6 MB
    float* el       = feat + (size_t)N_NODES * 64;           // N*4
    float* er       = el   + (size_t)N_NODES * 4;            // N*4
    int*   deg      = (int*)(er + (size_t)N_NODES * 4);      // N
    int*   rowptr   = deg + N_NODES;                         // N
    int*   edge_src = rowptr + N_NODES;                      // E = 6.4 MB
    int*   gtotal   = edge_src + N_EDGES;                    // 1
    // rank lives in d_out's first 6.4 MB: dead scratch until k5 overwrites
    // every element of out (wave per node writes all 64 lanes).
    int*   rank     = (int*)d_out;                           // E

    k1_project<<<2048, 256, 0, stream>>>(x, W, attn_l, attn_r, feat, el, er, deg, gtotal);
    k2_hist_rank<<<(N_EDGES / 4 + 255) / 256, 256, 0, stream>>>(dst, deg, rank);
    k3_segbase<<<(N_NODES + 255) / 256, 256, 0, stream>>>(deg, rowptr, gtotal);
    const int nodesPerPass = (N_NODES + NPASS - 1) / NPASS;
    for (int p = 0; p < NPASS; ++p) {
        int lo = p * nodesPerPass;
        int hi = min(N_NODES, lo + nodesPerPass);
        k4_fill_phase<<<(N_EDGES / 4 + 255) / 256, 256, 0, stream>>>(src, dst, rank,
                                                                     rowptr, edge_src, lo, hi);
    }
    k5_gather<<<(N_NODES * 64 + 255) / 256, 256, 0, stream>>>(rowptr, deg, edge_src,
                                                              el, er, feat, bias, out);
}

// Round 16
// 304.236 us; speedup vs baseline: 1.6374x; 1.0045x over previous
//
#include <hip/hip_runtime.h>
#include <math.h>

#define N_NODES 100000
#define N_EDGES 1600000
#define NEG_SLOPE 0.2f
#define NPASS 1                      // atomic-free fill: try single pass (6.4 MB region)

// ============================================================================
// k1: per-node projection feat = x @ W (thread owns col, W in VGPRs, x via
//     wave-uniform broadcast float4 loads), logits el/er, zero deg counters.
//     (round-11 confirmed: 96 -> ~42 us; unchanged)
// ============================================================================
__global__ __launch_bounds__(256) void k1_project(
        const float* __restrict__ x, const float* __restrict__ W,
        const float* __restrict__ attn_l, const float* __restrict__ attn_r,
        float* __restrict__ feat, float* __restrict__ el, float* __restrict__ er,
        int* __restrict__ deg, int* __restrict__ gtotal) {
    int t    = threadIdx.x;
    int lane = t & 63;
    int wib  = t >> 6;                                  // wave in block, 0..3
    int h    = lane >> 4;
    if (blockIdx.x == 0 && t == 0) *gtotal = 0;

    float w[64];                                        // W[:, lane] in VGPRs
    #pragma unroll
    for (int k = 0; k < 64; ++k) w[k] = W[k * 64 + lane];   // coalesced per k

    float al = attn_l[lane];                            // attn_l is flat [4*16]
    float ar = attn_r[lane];
    int wavesTotal = (gridDim.x * blockDim.x) >> 6;

    for (int n = blockIdx.x * 4 + wib; n < N_NODES; n += wavesTotal) {
        int nu = __builtin_amdgcn_readfirstlane(n);     // force wave-uniform base
        const float4* xr = (const float4*)(x + (size_t)nu * 64);
        float a0 = 0.f, a1 = 0.f, a2 = 0.f, a3 = 0.f;   // 4 independent chains
        #pragma unroll
        for (int kq = 0; kq < 16; ++kq) {
            float4 xq = xr[kq];                         // uniform addr -> broadcast
            a0 = fmaf(xq.x, w[4 * kq + 0], a0);
            a1 = fmaf(xq.y, w[4 * kq + 1], a1);
            a2 = fmaf(xq.z, w[4 * kq + 2], a2);
            a3 = fmaf(xq.w, w[4 * kq + 3], a3);
        }
        float acc = (a0 + a1) + (a2 + a3);
        feat[n * 64 + lane] = acc;
        float vl = acc * al, vr = acc * ar;
        #pragma unroll
        for (int off = 8; off >= 1; off >>= 1) {        // reduce within 16-lane head group
            vl += __shfl_xor(vl, off, 64);
            vr += __shfl_xor(vr, off, 64);
        }
        if ((lane & 15) == 0) {
            el[n * 4 + h] = vl;
            er[n * 4 + h] = vr;
        }
        if (lane == 0) deg[n] = 0;                      // zero degree counter
    }
}

// ============================================================================
// k2: histogram + RANK RECORDING, SCALAR 1 edge/thread.
//     Round-15 change: int4-packed atomics reverted — round-8 measured the
//     identical 4-chain-per-thread atomic structure as a REGRESSION (127->137
//     us, occupancy 75->42%).  Scalar maximizes thread-level parallelism for
//     a throughput-bound atomic stream; dst read + rank store stay coalesced.
// ============================================================================
__global__ __launch_bounds__(256) void k2_hist_rank(
        const int* __restrict__ dst, int* __restrict__ deg, int* __restrict__ rank) {
    int e = blockIdx.x * blockDim.x + threadIdx.x;
    if (e < N_EDGES) rank[e] = atomicAdd(&deg[dst[e]], 1);
}

// ============================================================================
// k3: rowptr[n] = exclusive prefix of deg (segment order irrelevant ->
//     wave-local shfl prefix + ONE global atomicAdd per wave).  deg is kept
//     intact (k5 needs it for segment end).
// ============================================================================
__global__ __launch_bounds__(256) void k3_segbase(
        const int* __restrict__ deg, int* __restrict__ rowptr, int* __restrict__ gtotal) {
    int tid  = blockIdx.x * blockDim.x + threadIdx.x;
    int lane = threadIdx.x & 63;
    int n    = tid;
    int dg   = (n < N_NODES) ? deg[n] : 0;
    int incl = dg;
    #pragma unroll
    for (int off = 1; off < 64; off <<= 1) {
        int v = __shfl_up(incl, off, 64);
        if (lane >= off) incl += v;
    }
    int waveTotal = __shfl(incl, 63, 64);
    int base = 0;
    if (lane == 63) base = atomicAdd(gtotal, waveTotal);
    base = __shfl(base, 63, 64);
    if (n < N_NODES) rowptr[n] = base + incl - dg;      // exclusive prefix
}

// ============================================================================
// k4: ATOMIC-FREE fill — pos = rowptr[d] + rank[e]; int4 loads + 4
//     independent scatter-store chains (no atomics -> MLP safe).  NPASS=1
//     this round: pure stores, 6.4 MB region (1.6x per-XCD L2) — trading
//     possible partial eviction thrash for 19.2 MB fewer re-reads + 1 launch.
//     Tripwire: if k4 enters top-5 with WRITE_SIZE >> 15 MB, revert NPASS=2.
// ============================================================================
__global__ __launch_bounds__(256) void k4_fill_phase(
        const int* __restrict__ src, const int* __restrict__ dst,
        const int* __restrict__ rank, const int* __restrict__ rowptr,
        int* __restrict__ edge_src, int lo, int hi) {
    int t = blockIdx.x * blockDim.x + threadIdx.x;
    if (t >= N_EDGES / 4) return;
    int4 d = ((const int4*)dst)[t];                     // 16B coalesced
    int4 s = ((const int4*)src)[t];
    int4 r = ((const int4*)rank)[t];
    if (d.x >= lo && d.x < hi) edge_src[rowptr[d.x] + r.x] = s.x;
    if (d.y >= lo && d.y < hi) edge_src[rowptr[d.y] + r.y] = s.y;
    if (d.z >= lo && d.z < hi) edge_src[rowptr[d.z] + r.z] = s.z;
    if (d.w >= lo && d.w < hi) edge_src[rowptr[d.w] + r.w] = s.w;
}

// ============================================================================
// k5: gather-aggregate, chunk-parallel softmax.  One wave per dst node.
//     (round-15 confirmed: 73.4 us; UNTOUCHED — control for this round's
//     build-chain changes.  Fixed 16-iteration phase B: round-12 proved a
//     data-dependent break kills the 16-deep load pipeline while padded
//     gathers are cache-hits.)
// ============================================================================
__global__ __launch_bounds__(256) void k5_gather(
        const int* __restrict__ rowptr, const int* __restrict__ deg,
        const int* __restrict__ edge_src,
        const float* __restrict__ el, const float* __restrict__ er,
        const float* __restrict__ feat, const float* __restrict__ bias,
        float* __restrict__ out) {
    int lane = threadIdx.x & 63;
    int h    = lane >> 4;                                // head for score phase
    int e16  = lane & 15;                                // edge slot in chunk
    int n    = (blockIdx.x * blockDim.x + threadIdx.x) >> 6;   // wave id == node
    if (n >= N_NODES) return;

    int   row0 = rowptr[n];                              // broadcast loads
    int   row1 = row0 + deg[n];
    float er_h = er[n * 4 + h];
    float bv   = bias[lane];
    int   pbase = lane & 48;                             // head-group base lane

    float m = -INFINITY, dnm = 0.f, acc = 0.f;
    for (int base = row0; base < row1; base += 16) {
        // ---- phase A: parallel scores for 16 edges x 4 heads ----
        int  ei    = base + e16;
        bool valid = ei < row1;
        int  s     = edge_src[valid ? ei : row0];        // clamp to a real edge
        float raw  = el[s * 4 + h] + er_h;               // 16B segment per edge
        raw = raw > 0.f ? raw : NEG_SLOPE * raw;         // leaky relu
        float sc = valid ? raw : -INFINITY;
        float cm = sc;                                   // chunk max (per head group)
        cm = fmaxf(cm, __shfl_xor(cm, 1, 64));
        cm = fmaxf(cm, __shfl_xor(cm, 2, 64));
        cm = fmaxf(cm, __shfl_xor(cm, 4, 64));
        cm = fmaxf(cm, __shfl_xor(cm, 8, 64));
        float mn = fmaxf(m, cm);
        float rs = __expf(m - mn);                       // chunk-level rescale
        float p  = __expf(sc - mn);                      // 0 for invalid lanes
        float ps = p;                                    // chunk denom sum
        ps += __shfl_xor(ps, 1, 64);
        ps += __shfl_xor(ps, 2, 64);
        ps += __shfl_xor(ps, 4, 64);
        ps += __shfl_xor(ps, 8, 64);
        dnm = dnm * rs + ps;
        acc *= rs;
        m = mn;
        // ---- phase B: 16 weighted feat rows, fixed trip count so all 16
        //      gathers pipeline; padded j's re-read a cached row (free) ----
        #pragma unroll
        for (int j = 0; j < 16; ++j) {
            float pj = __shfl(p, pbase + j, 64);         // p of (edge j, my head)
            int   sj = __shfl(s, j, 64);                 // uniform -> readlane
            float fa = feat[sj * 64 + lane];             // coalesced 256B row
            acc = fmaf(pj, fa, acc);                     // pj==0 for invalid j
        }
    }
    out[n * 64 + lane] = (dnm > 0.f ? acc / dnm : 0.f) + bv;
}

// ============================================================================
extern "C" void kernel_launch(void* const* d_in, const int* in_sizes, int n_in,
                              void* d_out, int out_size, void* d_ws, size_t ws_size,
                              hipStream_t stream) {
    const float* x      = (const float*)d_in[0];
    const float* W      = (const float*)d_in[1];
    const float* attn_l = (const float*)d_in[2];
    const float* attn_r = (const float*)d_in[3];
    const float* bias   = (const float*)d_in[4];
    const int*   src    = (const int*)d_in[5];
    const int*   dst    = (const int*)d_in[6];
    float* out = (float*)d_out;

    // workspace layout
    float* feat     = (float*)d_ws;                          // N*64 f32 = 25.6 MB
    float* el       = feat + (size_t)N_NODES * 64;           // N*4
    float* er       = el   + (size_t)N_NODES * 4;            // N*4
    int*   deg      = (int*)(er + (size_t)N_NODES * 4);      // N
    int*   rowptr   = deg + N_NODES;                         // N
    int*   edge_src = rowptr + N_NODES;                      // E = 6.4 MB
    int*   gtotal   = edge_src + N_EDGES;                    // 1
    // rank lives in d_out's first 6.4 MB: dead scratch until k5 overwrites
    // every element of out (wave per node writes all 64 lanes).
    int*   rank     = (int*)d_out;                           // E

    k1_project<<<2048, 256, 0, stream>>>(x, W, attn_l, attn_r, feat, el, er, deg, gtotal);
    k2_hist_rank<<<(N_EDGES + 255) / 256, 256, 0, stream>>>(dst, deg, rank);
    k3_segbase<<<(N_NODES + 255) / 256, 256, 0, stream>>>(deg, rowptr, gtotal);
    const int nodesPerPass = (N_NODES + NPASS - 1) / NPASS;
    for (int p = 0; p < NPASS; ++p) {
        int lo = p * nodesPerPass;
        int hi = min(N_NODES, lo + nodesPerPass);
        k4_fill_phase<<<(N_EDGES / 4 + 255) / 256, 256, 0, stream>>>(src, dst, rank,
                                                                     rowptr, edge_src, lo, hi);
    }
    k5_gather<<<(N_NODES * 64 + 255) / 256, 256, 0, stream>>>(rowptr, deg, edge_src,
                                                              el, er, feat, bias, out);
}

// Round 18
// 290.294 us; speedup vs baseline: 1.7160x; 1.0480x over previous
//
#include <hip/hip_runtime.h>
#include <math.h>

#define N_NODES 100000
#define N_EDGES 1600000
#define NEG_SLOPE 0.2f
#define NPASS 1                      // atomic-free fill, single pass (round-16: = 2-pass)
#define G_BLOCKS 7296                // fused kernel grid: 1043 proj + 6253 hist blocks

// ============================================================================
// F1: FUSED projection || histogram.  Round-16 budget analysis: k1,k2,k4 each
//     ~50-73 us (none in top-5, sum ~215).  k1 (VMEM-latency-bound) and k2
//     (atomic-latency-bound) are data-independent -> block-role fusion, roles
//     interleaved by bid%7 so every CU hosts both from t=0; expected
//     max(k1,k2) instead of k1+k2.  deg/gtotal zeroing moved to memset.
//
//     proj role (bid%7==0, 1043 blocks): feat = x @ W (thread owns col,
//     W[:,lane] in 64 VGPRs, x via wave-uniform broadcast float4), el/er
//     logits via 16-lane-group shfl reduce.  (round-11 structure, unchanged)
//     hist role (else, 6253 blocks): rank[e] = atomicAdd(&deg[dst[e]], 1),
//     scalar 1 edge/thread (round-15/16: = int4 variant).
// ============================================================================
__global__ __launch_bounds__(256) void f1_proj_hist(
        const float* __restrict__ x, const float* __restrict__ W,
        const float* __restrict__ attn_l, const float* __restrict__ attn_r,
        const int* __restrict__ dst,
        float* __restrict__ feat, float* __restrict__ el, float* __restrict__ er,
        int* __restrict__ deg, int* __restrict__ rank) {
    int bid = blockIdx.x;
    int t   = threadIdx.x;
    if (bid % 7 == 0) {
        // ---------------- projection role ----------------
        const int NPROJ = (G_BLOCKS + 6) / 7;           // 1043 blocks
        int p    = bid / 7;
        int lane = t & 63;
        int wib  = t >> 6;
        int h    = lane >> 4;
        float w[64];                                    // W[:, lane] in VGPRs
        #pragma unroll
        for (int k = 0; k < 64; ++k) w[k] = W[k * 64 + lane];
        float al = attn_l[lane];
        float ar = attn_r[lane];
        int stride = NPROJ * 4;                         // waves in proj role
        for (int n = p * 4 + wib; n < N_NODES; n += stride) {
            int nu = __builtin_amdgcn_readfirstlane(n); // wave-uniform base
            const float4* xr = (const float4*)(x + (size_t)nu * 64);
            float a0 = 0.f, a1 = 0.f, a2 = 0.f, a3 = 0.f;
            #pragma unroll
            for (int kq = 0; kq < 16; ++kq) {
                float4 xq = xr[kq];                     // uniform addr -> broadcast
                a0 = fmaf(xq.x, w[4 * kq + 0], a0);
                a1 = fmaf(xq.y, w[4 * kq + 1], a1);
                a2 = fmaf(xq.z, w[4 * kq + 2], a2);
                a3 = fmaf(xq.w, w[4 * kq + 3], a3);
            }
            float acc = (a0 + a1) + (a2 + a3);
            feat[n * 64 + lane] = acc;
            float vl = acc * al, vr = acc * ar;
            #pragma unroll
            for (int off = 8; off >= 1; off >>= 1) {    // 16-lane head-group reduce
                vl += __shfl_xor(vl, off, 64);
                vr += __shfl_xor(vr, off, 64);
            }
            if ((lane & 15) == 0) {
                el[n * 4 + h] = vl;
                er[n * 4 + h] = vr;
            }
        }
    } else {
        // ---------------- histogram role ----------------
        int hr = bid - (bid + 6) / 7;                   // rank among non-proj blocks
        int e  = hr * 256 + t;
        if (e < N_EDGES) rank[e] = atomicAdd(&deg[dst[e]], 1);
    }
}

// ============================================================================
// k3: rowptr[n] = exclusive prefix of deg (segment order irrelevant ->
//     wave-local shfl prefix + ONE global atomicAdd per wave).  deg intact.
// ============================================================================
__global__ __launch_bounds__(256) void k3_segbase(
        const int* __restrict__ deg, int* __restrict__ rowptr, int* __restrict__ gtotal) {
    int tid  = blockIdx.x * blockDim.x + threadIdx.x;
    int lane = threadIdx.x & 63;
    int n    = tid;
    int dg   = (n < N_NODES) ? deg[n] : 0;
    int incl = dg;
    #pragma unroll
    for (int off = 1; off < 64; off <<= 1) {
        int v = __shfl_up(incl, off, 64);
        if (lane >= off) incl += v;
    }
    int waveTotal = __shfl(incl, 63, 64);
    int base = 0;
    if (lane == 63) base = atomicAdd(gtotal, waveTotal);
    base = __shfl(base, 63, 64);
    if (n < N_NODES) rowptr[n] = base + incl - dg;      // exclusive prefix
}

// ============================================================================
// k4: ATOMIC-FREE fill — pos = rowptr[d] + rank[e]; int4 loads + 4
//     independent scatter-store chains.  NPASS=1 (round-16: = 2-pass).
// ============================================================================
__global__ __launch_bounds__(256) void k4_fill_phase(
        const int* __restrict__ src, const int* __restrict__ dst,
        const int* __restrict__ rank, const int* __restrict__ rowptr,
        int* __restrict__ edge_src, int lo, int hi) {
    int t = blockIdx.x * blockDim.x + threadIdx.x;
    if (t >= N_EDGES / 4) return;
    int4 d = ((const int4*)dst)[t];                     // 16B coalesced
    int4 s = ((const int4*)src)[t];
    int4 r = ((const int4*)rank)[t];
    if (d.x >= lo && d.x < hi) edge_src[rowptr[d.x] + r.x] = s.x;
    if (d.y >= lo && d.y < hi) edge_src[rowptr[d.y] + r.y] = s.y;
    if (d.z >= lo && d.z < hi) edge_src[rowptr[d.z] + r.z] = s.z;
    if (d.w >= lo && d.w < hi) edge_src[rowptr[d.w] + r.w] = s.w;
}

// ============================================================================
// k5: gather-aggregate, chunk-parallel softmax.  One wave per dst node.
//     (73.2 us rounds 15/16; UNTOUCHED — control.  Fixed 16-iter phase B:
//     round-12 proved data-dependent break kills the load pipeline while
//     padded gathers are cache-hits.)
// ============================================================================
__global__ __launch_bounds__(256) void k5_gather(
        const int* __restrict__ rowptr, const int* __restrict__ deg,
        const int* __restrict__ edge_src,
        const float* __restrict__ el, const float* __restrict__ er,
        const float* __restrict__ feat, const float* __restrict__ bias,
        float* __restrict__ out) {
    int lane = threadIdx.x & 63;
    int h    = lane >> 4;                                // head for score phase
    int e16  = lane & 15;                                // edge slot in chunk
    int n    = (blockIdx.x * blockDim.x + threadIdx.x) >> 6;   // wave id == node
    if (n >= N_NODES) return;

    int   row0 = rowptr[n];                              // broadcast loads
    int   row1 = row0 + deg[n];
    float er_h = er[n * 4 + h];
    float bv   = bias[lane];
    int   pbase = lane & 48;                             // head-group base lane

    float m = -INFINITY, dnm = 0.f, acc = 0.f;
    for (int base = row0; base < row1; base += 16) {
        // ---- phase A: parallel scores for 16 edges x 4 heads ----
        int  ei    = base + e16;
        bool valid = ei < row1;
        int  s     = edge_src[valid ? ei : row0];        // clamp to a real edge
        float raw  = el[s * 4 + h] + er_h;               // 16B segment per edge
        raw = raw > 0.f ? raw : NEG_SLOPE * raw;         // leaky relu
        float sc = valid ? raw : -INFINITY;
        float cm = sc;                                   // chunk max (per head group)
        cm = fmaxf(cm, __shfl_xor(cm, 1, 64));
        cm = fmaxf(cm, __shfl_xor(cm, 2, 64));
        cm = fmaxf(cm, __shfl_xor(cm, 4, 64));
        cm = fmaxf(cm, __shfl_xor(cm, 8, 64));
        float mn = fmaxf(m, cm);
        float rs = __expf(m - mn);                       // chunk-level rescale
        float p  = __expf(sc - mn);                      // 0 for invalid lanes
        float ps = p;                                    // chunk denom sum
        ps += __shfl_xor(ps, 1, 64);
        ps += __shfl_xor(ps, 2, 64);
        ps += __shfl_xor(ps, 4, 64);
        ps += __shfl_xor(ps, 8, 64);
        dnm = dnm * rs + ps;
        acc *= rs;
        m = mn;
        // ---- phase B: 16 weighted feat rows, fixed trip count so all 16
        //      gathers pipeline; padded j's re-read a cached row (free) ----
        #pragma unroll
        for (int j = 0; j < 16; ++j) {
            float pj = __shfl(p, pbase + j, 64);         // p of (edge j, my head)
            int   sj = __shfl(s, j, 64);                 // uniform -> readlane
            float fa = feat[sj * 64 + lane];             // coalesced 256B row
            acc = fmaf(pj, fa, acc);                     // pj==0 for invalid j
        }
    }
    out[n * 64 + lane] = (dnm > 0.f ? acc / dnm : 0.f) + bv;
}

// ============================================================================
extern "C" void kernel_launch(void* const* d_in, const int* in_sizes, int n_in,
                              void* d_out, int out_size, void* d_ws, size_t ws_size,
                              hipStream_t stream) {
    const float* x      = (const float*)d_in[0];
    const float* W      = (const float*)d_in[1];
    const float* attn_l = (const float*)d_in[2];
    const float* attn_r = (const float*)d_in[3];
    const float* bias   = (const float*)d_in[4];
    const int*   src    = (const int*)d_in[5];
    const int*   dst    = (const int*)d_in[6];
    float* out = (float*)d_out;

    // workspace layout — deg and gtotal CONTIGUOUS for one memset
    float* feat     = (float*)d_ws;                          // N*64 f32 = 25.6 MB
    float* el       = feat + (size_t)N_NODES * 64;           // N*4
    float* er       = el   + (size_t)N_NODES * 4;            // N*4
    int*   deg      = (int*)(er + (size_t)N_NODES * 4);      // N
    int*   gtotal   = deg + N_NODES;                         // 1   (adjacent to deg)
    int*   rowptr   = gtotal + 1;                            // N
    int*   edge_src = rowptr + N_NODES;                      // E = 6.4 MB
    // rank lives in d_out's first 6.4 MB: dead scratch until k5 overwrites
    // every element of out (wave per node writes all 64 lanes).
    int*   rank     = (int*)d_out;                           // E

    hipMemsetAsync(deg, 0, (size_t)(N_NODES + 1) * sizeof(int), stream);  // deg + gtotal
    f1_proj_hist<<<G_BLOCKS, 256, 0, stream>>>(x, W, attn_l, attn_r, dst,
                                               feat, el, er, deg, rank);
    k3_segbase<<<(N_NODES + 255) / 256, 256, 0, stream>>>(deg, rowptr, gtotal);
    const int nodesPerPass = (N_NODES + NPASS - 1) / NPASS;
    for (int p = 0; p < NPASS; ++p) {
        int lo = p * nodesPerPass;
        int hi = min(N_NODES, lo + nodesPerPass);
        k4_fill_phase<<<(N_EDGES / 4 + 255) / 256, 256, 0, stream>>>(src, dst, rank,
                                                                     rowptr, edge_src, lo, hi);
    }
    k5_gather<<<(N_NODES * 64 + 255) / 256, 256, 0, stream>>>(rowptr, deg, edge_src,
                                                              el, er, feat, bias, out);
}